// Round 1
// baseline (215.156 us; speedup 1.0000x reference)
//
#include <hip/hip_runtime.h>

// Problem constants (from reference)
#define L_TOTAL   32768
#define E_DIM     64
#define K_TOTAL   1024
#define KSPLIT    4
#define KPB       (K_TOTAL / KSPLIT)   // 256 k's per block
#define KCHUNK    64                   // k's staged in LDS per pass
#define TPB       256

#define OUT_STRIDE 2097152             // L_TOTAL * E_DIM

// ---------------------------------------------------------------------------
// Kernel 1: per-latent argmin over a K-split range.
// grid = 128 latent-groups x 4 k-splits = 512 blocks, 256 threads each.
// Lane i of block handles latent (group*256 + i), scanning KPB embeddings.
// x row lives in 16 float4 VGPRs; embedding chunk staged in LDS, read with
// wave-uniform addresses (broadcast, conflict-free).
// ---------------------------------------------------------------------------
__global__ __launch_bounds__(TPB, 2)
void vq_argmin_kernel(const float* __restrict__ x,
                      const float* __restrict__ emb,
                      float2* __restrict__ partial) {
    __shared__ float  s_en[KPB];                  // ||e_k||^2 for this block's range
    __shared__ float4 s_e[KCHUNK * (E_DIM / 4)];  // 64 rows x 16 float4 = 16 KB

    const int tid   = threadIdx.x;
    const int lb    = blockIdx.x >> 2;    // latent group 0..127
    const int ks    = blockIdx.x & 3;     // k-split     0..3
    const int kbase = ks * KPB;
    const int lat   = lb * TPB + tid;

    // ---- embedding norms for this block's k-range: thread t -> k = kbase+t
    {
        const float4* er = (const float4*)(emb + (size_t)(kbase + tid) * E_DIM);
        float n0 = 0.f, n1 = 0.f, n2 = 0.f, n3 = 0.f;
        #pragma unroll
        for (int g = 0; g < 16; ++g) {
            float4 v = er[g];
            n0 = fmaf(v.x, v.x, n0);
            n1 = fmaf(v.y, v.y, n1);
            n2 = fmaf(v.z, v.z, n2);
            n3 = fmaf(v.w, v.w, n3);
        }
        s_en[tid] = (n0 + n1) + (n2 + n3);
    }

    // ---- x row into registers + ||x||^2
    float4 xr[16];
    float  xx;
    {
        const float4* xrow = (const float4*)(x + (size_t)lat * E_DIM);
        float n0 = 0.f, n1 = 0.f, n2 = 0.f, n3 = 0.f;
        #pragma unroll
        for (int g = 0; g < 16; ++g) {
            xr[g] = xrow[g];
            n0 = fmaf(xr[g].x, xr[g].x, n0);
            n1 = fmaf(xr[g].y, xr[g].y, n1);
            n2 = fmaf(xr[g].z, xr[g].z, n2);
            n3 = fmaf(xr[g].w, xr[g].w, n3);
        }
        xx = (n0 + n1) + (n2 + n3);
    }

    float best = 3.402823466e+38f;
    int   bidx = 0;

    #pragma unroll 1
    for (int c = 0; c < KPB / KCHUNK; ++c) {
        __syncthreads();  // previous chunk's readers done (also covers s_en init)
        // stage 64 embedding rows: 1024 float4, 4 per thread, coalesced
        const float4* src = (const float4*)(emb + (size_t)(kbase + c * KCHUNK) * E_DIM);
        #pragma unroll
        for (int i = 0; i < 4; ++i)
            s_e[tid + i * TPB] = src[tid + i * TPB];
        __syncthreads();

        #pragma unroll 2
        for (int kk = 0; kk < KCHUNK; ++kk) {
            const float4* ev = &s_e[kk * 16];
            float d0 = 0.f, d1 = 0.f, d2 = 0.f, d3 = 0.f;
            #pragma unroll
            for (int g = 0; g < 16; ++g) {
                float4 e4 = ev[g];   // wave-uniform address -> LDS broadcast
                d0 = fmaf(xr[g].x, e4.x, d0);
                d1 = fmaf(xr[g].y, e4.y, d1);
                d2 = fmaf(xr[g].z, e4.z, d2);
                d3 = fmaf(xr[g].w, e4.w, d3);
            }
            float dot  = (d0 + d1) + (d2 + d3);
            // mirror reference: (||x||^2 - 2*dot) + ||e||^2
            float dist = fmaf(-2.0f, dot, xx) + s_en[c * KCHUNK + kk];
            int   kg   = kbase + c * KCHUNK + kk;
            if (dist < best) { best = dist; bidx = kg; }  // strict < keeps first occurrence
        }
    }

    partial[(size_t)lat * KSPLIT + ks] = make_float2(best, __int_as_float(bidx));
}

// ---------------------------------------------------------------------------
// Kernel 2: merge the 4 K-split partials per latent (lexicographic: value,
// then lower index == numpy first-occurrence argmin). Writes the int index
// to workspace (for the gather) and the float index to d_out tail.
// ---------------------------------------------------------------------------
__global__ __launch_bounds__(TPB)
void vq_reduce_kernel(const float2* __restrict__ partial,
                      int* __restrict__ idx_ws,
                      float* __restrict__ out_idx) {
    const int l = blockIdx.x * blockDim.x + threadIdx.x;  // 0..32767
    float best = 3.402823466e+38f;
    int   bidx = 0x7fffffff;
    #pragma unroll
    for (int s = 0; s < KSPLIT; ++s) {
        float2 p = partial[(size_t)l * KSPLIT + s];
        int    i = __float_as_int(p.y);
        if (p.x < best || (p.x == best && i < bidx)) { best = p.x; bidx = i; }
    }
    idx_ws[l]  = bidx;
    out_idx[l] = (float)bidx;
}

// ---------------------------------------------------------------------------
// Kernel 3: elementwise epilogue, float4-vectorized & coalesced.
// out0 = x, out1 = quantized = emb[idx], out2 = z_hat = (x + q) - x
// (rounding order preserved -- no fast-math folding to q).
// ---------------------------------------------------------------------------
__global__ __launch_bounds__(TPB)
void vq_epilogue_kernel(const float* __restrict__ x,
                        const float* __restrict__ emb,
                        const int* __restrict__ idx_ws,
                        float* __restrict__ out) {
    const int i = blockIdx.x * blockDim.x + threadIdx.x;  // 0..524287 (float4 units)
    const int l = i >> 4;
    const int g = i & 15;
    const int idx = idx_ws[l];

    const float4 xv = ((const float4*)x)[i];
    const float4 qv = ((const float4*)emb)[idx * 16 + g];  // 256 KB codebook, L2-hot

    float4 z;
    z.x = (xv.x + qv.x) - xv.x;
    z.y = (xv.y + qv.y) - xv.y;
    z.z = (xv.z + qv.z) - xv.z;
    z.w = (xv.w + qv.w) - xv.w;

    ((float4*)out)[i]                    = xv;
    ((float4*)(out + OUT_STRIDE))[i]     = qv;
    ((float4*)(out + 2 * OUT_STRIDE))[i] = z;
}

// ---------------------------------------------------------------------------
extern "C" void kernel_launch(void* const* d_in, const int* in_sizes, int n_in,
                              void* d_out, int out_size, void* d_ws, size_t ws_size,
                              hipStream_t stream) {
    const float* x   = (const float*)d_in[0];   // 32768*64 fp32
    const float* emb = (const float*)d_in[1];   // 1024*64 fp32
    float* out = (float*)d_out;

    float2* partial = (float2*)d_ws;                               // 32768*4*8B = 1 MB
    int*    idx_ws  = (int*)((char*)d_ws + (size_t)L_TOTAL * KSPLIT * sizeof(float2));

    hipLaunchKernelGGL(vq_argmin_kernel, dim3(L_TOTAL / TPB * KSPLIT), dim3(TPB), 0, stream,
                       x, emb, partial);
    hipLaunchKernelGGL(vq_reduce_kernel, dim3(L_TOTAL / TPB), dim3(TPB), 0, stream,
                       partial, idx_ws, out + 3 * (size_t)OUT_STRIDE);
    hipLaunchKernelGGL(vq_epilogue_kernel, dim3((L_TOTAL * E_DIM / 4) / TPB), dim3(TPB), 0, stream,
                       x, emb, idx_ws, out);
}

// Round 2
// 117.675 us; speedup vs baseline: 1.8284x; 1.8284x over previous
//
#include <hip/hip_runtime.h>

#define L_TOTAL   32768
#define E_DIM     64
#define K_TOTAL   1024
#define OUT_STRIDE 2097152            // L_TOTAL * E_DIM

typedef _Float16 half_t;
typedef _Float16 half8  __attribute__((ext_vector_type(8)));
typedef float    floatx4 __attribute__((ext_vector_type(4)));

// Workspace layout (bytes)
#define WS_XH  0u                      // x_hi  f16 [32768*64]  4 MB
#define WS_XL  4194304u                // x_lo  f16 [32768*64]  4 MB
#define WS_EH  8388608u                // e_hi  f16 [1024*64]   128 KB
#define WS_EL  8519680u                // e_lo  f16 [1024*64]   128 KB
#define WS_XX  8650752u                // ||x||^2 f32 [32768]   128 KB
#define WS_EN  8781824u                // ||e||^2 f32 [1024]    4 KB
#define WS_IDX 8785920u                // argmin idx i32 [32768] 128 KB

// ---------------------------------------------------------------------------
// Convert fp32 rows (64 wide) to f16 hi + f16 lo, and compute row norms.
// 4 threads per row, 16 elements each. Fully coalesced 32B stores.
// ---------------------------------------------------------------------------
__global__ __launch_bounds__(256)
void vq_convert_kernel(const float* __restrict__ src,
                       half_t* __restrict__ hi, half_t* __restrict__ lo,
                       float* __restrict__ norms) {
    const int t   = blockIdx.x * blockDim.x + threadIdx.x;  // one per 16 floats
    const int row = t >> 2;
    const float4* s4 = ((const float4*)src) + (size_t)t * 4;

    half8 h0, h1, l0, l1;
    float n = 0.f;
    #pragma unroll
    for (int g = 0; g < 2; ++g) {
        float4 v = s4[g];
        float vv[4] = {v.x, v.y, v.z, v.w};
        #pragma unroll
        for (int j = 0; j < 4; ++j) {
            float f = vv[j];
            half_t hh = (half_t)f;
            half_t ll = (half_t)(f - (float)hh);
            h0[g * 4 + j] = hh;
            l0[g * 4 + j] = ll;
            n = fmaf(f, f, n);
        }
    }
    #pragma unroll
    for (int g = 0; g < 2; ++g) {
        float4 v = s4[2 + g];
        float vv[4] = {v.x, v.y, v.z, v.w};
        #pragma unroll
        for (int j = 0; j < 4; ++j) {
            float f = vv[j];
            half_t hh = (half_t)f;
            half_t ll = (half_t)(f - (float)hh);
            h1[g * 4 + j] = hh;
            l1[g * 4 + j] = ll;
            n = fmaf(f, f, n);
        }
    }
    *(half8*)(hi + (size_t)t * 16)     = h0;
    *(half8*)(hi + (size_t)t * 16 + 8) = h1;
    *(half8*)(lo + (size_t)t * 16)     = l0;
    *(half8*)(lo + (size_t)t * 16 + 8) = l1;

    // reduce norm across the 4 row-mates (adjacent lanes)
    n += __shfl_xor(n, 1, 64);
    n += __shfl_xor(n, 2, 64);
    if ((t & 3) == 0) norms[row] = n;
}

// ---------------------------------------------------------------------------
// MFMA distance + argmin. One wave = 32 latents x all 1024 embeddings.
// dot(x,e) via f16 hi/lo split (3 passes, fp32 accum) on 16x16x32 MFMA.
// B fragments read directly from the L2-resident f16 codebook (no LDS).
// dist = (xx - 2*dot) + en computed in the reference's op order (no FMA).
// ---------------------------------------------------------------------------
__global__ __launch_bounds__(256)
void vq_mfma_argmin_kernel(const half_t* __restrict__ xh, const half_t* __restrict__ xl,
                           const half_t* __restrict__ eh, const half_t* __restrict__ el,
                           const float* __restrict__ xx, const float* __restrict__ en,
                           int* __restrict__ idx_out, float* __restrict__ fidx_out) {
    const int tid   = threadIdx.x;
    const int wave  = tid >> 6;
    const int lane  = tid & 63;
    const int q     = lane >> 4;       // quad 0..3
    const int ln    = lane & 15;       // col-lane 0..15
    const int mbase = blockIdx.x * 128 + wave * 32;

    // A fragments: A[m=ln][k=q*8+j], [row-tile][k-tile][hi/lo]
    half8 A[2][2][2];
    #pragma unroll
    for (int rt = 0; rt < 2; ++rt) {
        const size_t rbase = (size_t)(mbase + rt * 16 + ln) * E_DIM + q * 8;
        #pragma unroll
        for (int kt = 0; kt < 2; ++kt) {
            A[rt][kt][0] = *(const half8*)(xh + rbase + kt * 32);
            A[rt][kt][1] = *(const half8*)(xl + rbase + kt * 32);
        }
    }
    // ||x||^2 for the rows this lane's C-fragment holds (rows q*4+r)
    floatx4 xq[2];
    xq[0] = *(const floatx4*)(xx + mbase + q * 4);
    xq[1] = *(const floatx4*)(xx + mbase + 16 + q * 4);

    float best[2][4];
    int   bidx[2][4];
    #pragma unroll
    for (int rt = 0; rt < 2; ++rt)
        #pragma unroll
        for (int r = 0; r < 4; ++r) { best[rt][r] = 3.402823466e+38f; bidx[rt][r] = 0; }

    // B base for this lane: row (nt*16+ln), dims q*8..q*8+7
    const half_t* ehB = eh + (size_t)ln * E_DIM + q * 8;
    const half_t* elB = el + (size_t)ln * E_DIM + q * 8;
    const float*  enB = en + ln;

    #pragma unroll 4
    for (int nt = 0; nt < K_TOTAL / 16; ++nt) {
        half8 bh0 = *(const half8*)(ehB + nt * 1024);        // k-tile 0 (dims 0..31)
        half8 bh1 = *(const half8*)(ehB + nt * 1024 + 32);   // k-tile 1 (dims 32..63)
        half8 bl0 = *(const half8*)(elB + nt * 1024);
        half8 bl1 = *(const half8*)(elB + nt * 1024 + 32);
        float env = enB[nt * 16];
        const int kg = nt * 16 + ln;

        #pragma unroll
        for (int rt = 0; rt < 2; ++rt) {
            floatx4 Ca = {0.f, 0.f, 0.f, 0.f};
            floatx4 Cb = {0.f, 0.f, 0.f, 0.f};
            Ca = __builtin_amdgcn_mfma_f32_16x16x32_f16(A[rt][0][0], bh0, Ca, 0, 0, 0);
            Ca = __builtin_amdgcn_mfma_f32_16x16x32_f16(A[rt][1][0], bh1, Ca, 0, 0, 0);
            Cb = __builtin_amdgcn_mfma_f32_16x16x32_f16(A[rt][0][1], bh0, Cb, 0, 0, 0);
            Cb = __builtin_amdgcn_mfma_f32_16x16x32_f16(A[rt][1][1], bh1, Cb, 0, 0, 0);
            Cb = __builtin_amdgcn_mfma_f32_16x16x32_f16(A[rt][0][0], bl0, Cb, 0, 0, 0);
            Cb = __builtin_amdgcn_mfma_f32_16x16x32_f16(A[rt][1][0], bl1, Cb, 0, 0, 0);
            #pragma unroll
            for (int r = 0; r < 4; ++r) {
                float dot = Ca[r] + Cb[r];
                // reference op order: (xx - 2*dot) + en, no FMA contraction
                float d = __fadd_rn(__fsub_rn(xq[rt][r], __fmul_rn(2.0f, dot)), env);
                if (d < best[rt][r]) { best[rt][r] = d; bidx[rt][r] = kg; }
            }
        }
    }

    // argmin across the 16 col-lanes of each quad (ties -> lower index)
    #pragma unroll
    for (int off = 1; off < 16; off <<= 1) {
        #pragma unroll
        for (int rt = 0; rt < 2; ++rt)
            #pragma unroll
            for (int r = 0; r < 4; ++r) {
                float ob = __shfl_xor(best[rt][r], off, 64);
                int   oi = __shfl_xor(bidx[rt][r], off, 64);
                if (ob < best[rt][r] || (ob == best[rt][r] && oi < bidx[rt][r])) {
                    best[rt][r] = ob; bidx[rt][r] = oi;
                }
            }
    }
    if (ln == 0) {
        #pragma unroll
        for (int rt = 0; rt < 2; ++rt)
            #pragma unroll
            for (int r = 0; r < 4; ++r) {
                const int latent = mbase + rt * 16 + q * 4 + r;
                idx_out[latent]  = bidx[rt][r];
                fidx_out[latent] = (float)bidx[rt][r];
            }
    }
}

// ---------------------------------------------------------------------------
// Elementwise epilogue: out0 = x, out1 = emb[idx], out2 = (x + q) - x.
// ---------------------------------------------------------------------------
__global__ __launch_bounds__(256)
void vq_epilogue_kernel(const float* __restrict__ x,
                        const float* __restrict__ emb,
                        const int* __restrict__ idx_ws,
                        float* __restrict__ out) {
    const int i = blockIdx.x * blockDim.x + threadIdx.x;  // float4 units
    const int l = i >> 4;
    const int g = i & 15;
    const int idx = idx_ws[l];

    const float4 xv = ((const float4*)x)[i];
    const float4 qv = ((const float4*)emb)[idx * 16 + g];

    float4 z;
    z.x = (xv.x + qv.x) - xv.x;
    z.y = (xv.y + qv.y) - xv.y;
    z.z = (xv.z + qv.z) - xv.z;
    z.w = (xv.w + qv.w) - xv.w;

    ((float4*)out)[i]                    = xv;
    ((float4*)(out + OUT_STRIDE))[i]     = qv;
    ((float4*)(out + 2 * OUT_STRIDE))[i] = z;
}

// ---------------------------------------------------------------------------
extern "C" void kernel_launch(void* const* d_in, const int* in_sizes, int n_in,
                              void* d_out, int out_size, void* d_ws, size_t ws_size,
                              hipStream_t stream) {
    const float* x   = (const float*)d_in[0];
    const float* emb = (const float*)d_in[1];
    float* out = (float*)d_out;

    char* ws = (char*)d_ws;
    half_t* xh = (half_t*)(ws + WS_XH);
    half_t* xl = (half_t*)(ws + WS_XL);
    half_t* eh = (half_t*)(ws + WS_EH);
    half_t* el = (half_t*)(ws + WS_EL);
    float*  xx = (float*)(ws + WS_XX);
    float*  en = (float*)(ws + WS_EN);
    int*    idx = (int*)(ws + WS_IDX);

    // converts: 4 threads per row of 64
    hipLaunchKernelGGL(vq_convert_kernel, dim3(L_TOTAL * 4 / 256), dim3(256), 0, stream,
                       x, xh, xl, xx);
    hipLaunchKernelGGL(vq_convert_kernel, dim3(K_TOTAL * 4 / 256), dim3(256), 0, stream,
                       emb, eh, el, en);
    // MFMA distance + argmin: 256 blocks x 4 waves, 32 latents/wave
    hipLaunchKernelGGL(vq_mfma_argmin_kernel, dim3(L_TOTAL / 128), dim3(256), 0, stream,
                       xh, xl, eh, el, xx, en, idx, out + 3 * (size_t)OUT_STRIDE);
    // epilogue
    hipLaunchKernelGGL(vq_epilogue_kernel, dim3((L_TOTAL * E_DIM / 4) / 256), dim3(256), 0, stream,
                       x, emb, idx, out);
}

// Round 3
// 107.784 us; speedup vs baseline: 1.9962x; 1.0918x over previous
//
#include <hip/hip_runtime.h>

#define L_TOTAL   32768
#define E_DIM     64
#define K_TOTAL   1024
#define OUT_STRIDE 2097152            // L_TOTAL * E_DIM

typedef _Float16 half_t;
typedef _Float16 half8  __attribute__((ext_vector_type(8)));
typedef float    floatx4 __attribute__((ext_vector_type(4)));

// Workspace layout (bytes): only the f16 codebook + norms now
#define WS_EH  0u                      // e_hi  f16 [1024*64]   128 KB
#define WS_EL  131072u                 // e_lo  f16 [1024*64]   128 KB
#define WS_EN  262144u                 // ||e||^2 f32 [1024]    4 KB

// ---------------------------------------------------------------------------
// Convert fp32 rows (64 wide) to f16 hi + f16 lo, and compute row norms.
// 4 threads per row, 16 elements each. (codebook only: 16 blocks)
// ---------------------------------------------------------------------------
__global__ __launch_bounds__(256)
void vq_convert_kernel(const float* __restrict__ src,
                       half_t* __restrict__ hi, half_t* __restrict__ lo,
                       float* __restrict__ norms) {
    const int t   = blockIdx.x * blockDim.x + threadIdx.x;  // one per 16 floats
    const int row = t >> 2;
    const float4* s4 = ((const float4*)src) + (size_t)t * 4;

    half8 h0, h1, l0, l1;
    float n = 0.f;
    #pragma unroll
    for (int g = 0; g < 2; ++g) {
        float4 v = s4[g];
        float vv[4] = {v.x, v.y, v.z, v.w};
        #pragma unroll
        for (int j = 0; j < 4; ++j) {
            float f = vv[j];
            half_t hh = (half_t)f;
            half_t ll = (half_t)(f - (float)hh);
            h0[g * 4 + j] = hh;
            l0[g * 4 + j] = ll;
            n = fmaf(f, f, n);
        }
    }
    #pragma unroll
    for (int g = 0; g < 2; ++g) {
        float4 v = s4[2 + g];
        float vv[4] = {v.x, v.y, v.z, v.w};
        #pragma unroll
        for (int j = 0; j < 4; ++j) {
            float f = vv[j];
            half_t hh = (half_t)f;
            half_t ll = (half_t)(f - (float)hh);
            h1[g * 4 + j] = hh;
            l1[g * 4 + j] = ll;
            n = fmaf(f, f, n);
        }
    }
    *(half8*)(hi + (size_t)t * 16)     = h0;
    *(half8*)(hi + (size_t)t * 16 + 8) = h1;
    *(half8*)(lo + (size_t)t * 16)     = l0;
    *(half8*)(lo + (size_t)t * 16 + 8) = l1;

    n += __shfl_xor(n, 1, 64);
    n += __shfl_xor(n, 2, 64);
    if ((t & 3) == 0) norms[row] = n;
}

// ---------------------------------------------------------------------------
// Fused: hi/lo MFMA distances + argmin + merge + epilogue.
// Block = 4 waves, ALL owning the same 32 latents; wave ks scans K-quarter
// [ks*256, ks*256+256). Grid = L/32 = 1024 blocks -> ~16-20 waves/CU.
// x converted fp32->f16 hi/lo in-register; B read from L2-resident f16
// codebook; final argmin merged in LDS; epilogue written from registers.
// ---------------------------------------------------------------------------
__global__ __launch_bounds__(256, 4)
void vq_fused_kernel(const float* __restrict__ x,
                     const float* __restrict__ emb,
                     const half_t* __restrict__ eh, const half_t* __restrict__ el,
                     const float* __restrict__ en,
                     float* __restrict__ out) {
    __shared__ float s_best[4][32];
    __shared__ int   s_bidx[4][32];
    __shared__ int   s_fin[32];

    const int tid   = threadIdx.x;
    const int ks    = tid >> 6;        // K-split 0..3
    const int lane  = tid & 63;
    const int q     = lane >> 4;       // quad 0..3
    const int ln    = lane & 15;       // 0..15
    const int mbase = blockIdx.x * 32;
    const int kbase = ks * 256;

    // ---- load x tile (fp32), convert to hi/lo f16 fragments, row norms
    // lane (q,ln) holds row (rt*16+ln), dims {kt*32+q*8 .. +8}
    half8 A[2][2][2];                  // [rt][kt][hi/lo]
    float nrm[2];
    #pragma unroll
    for (int rt = 0; rt < 2; ++rt) {
        const float* xr = x + (size_t)(mbase + rt * 16 + ln) * E_DIM + q * 8;
        float s = 0.f;
        #pragma unroll
        for (int kt = 0; kt < 2; ++kt) {
            float4 v0 = *(const float4*)(xr + kt * 32);
            float4 v1 = *(const float4*)(xr + kt * 32 + 4);
            float f[8] = {v0.x, v0.y, v0.z, v0.w, v1.x, v1.y, v1.z, v1.w};
            #pragma unroll
            for (int j = 0; j < 8; ++j) {
                half_t hh = (half_t)f[j];
                half_t ll = (half_t)(f[j] - (float)hh);
                A[rt][kt][0][j] = hh;
                A[rt][kt][1][j] = ll;
                s = fmaf(f[j], f[j], s);
            }
        }
        s += __shfl_xor(s, 16, 64);    // reduce across the 4 q-lanes of this row
        s += __shfl_xor(s, 32, 64);
        nrm[rt] = s;                   // = ||x[row rt*16+ln]||^2, in every q
    }
    // C-fragment rows are q*4+r: fetch their norms via bpermute
    floatx4 xq[2];
    #pragma unroll
    for (int rt = 0; rt < 2; ++rt)
        #pragma unroll
        for (int r = 0; r < 4; ++r)
            xq[rt][r] = __shfl(nrm[rt], q * 4 + r, 64);

    float best[2][4];
    int   bidx[2][4];
    #pragma unroll
    for (int rt = 0; rt < 2; ++rt)
        #pragma unroll
        for (int r = 0; r < 4; ++r) { best[rt][r] = 3.402823466e+38f; bidx[rt][r] = 0; }

    const half_t* ehB = eh + (size_t)(kbase + ln) * E_DIM + q * 8;
    const half_t* elB = el + (size_t)(kbase + ln) * E_DIM + q * 8;
    const float*  enB = en + kbase + ln;

    #pragma unroll 2
    for (int nt = 0; nt < 16; ++nt) {
        half8 bh0 = *(const half8*)(ehB + nt * 1024);
        half8 bh1 = *(const half8*)(ehB + nt * 1024 + 32);
        half8 bl0 = *(const half8*)(elB + nt * 1024);
        half8 bl1 = *(const half8*)(elB + nt * 1024 + 32);
        float env = enB[nt * 16];
        const int kg = kbase + nt * 16 + ln;

        #pragma unroll
        for (int rt = 0; rt < 2; ++rt) {
            floatx4 Ca = {0.f, 0.f, 0.f, 0.f};
            floatx4 Cb = {0.f, 0.f, 0.f, 0.f};
            Ca = __builtin_amdgcn_mfma_f32_16x16x32_f16(A[rt][0][0], bh0, Ca, 0, 0, 0);
            Ca = __builtin_amdgcn_mfma_f32_16x16x32_f16(A[rt][1][0], bh1, Ca, 0, 0, 0);
            Cb = __builtin_amdgcn_mfma_f32_16x16x32_f16(A[rt][0][1], bh0, Cb, 0, 0, 0);
            Cb = __builtin_amdgcn_mfma_f32_16x16x32_f16(A[rt][1][1], bh1, Cb, 0, 0, 0);
            Cb = __builtin_amdgcn_mfma_f32_16x16x32_f16(A[rt][0][0], bl0, Cb, 0, 0, 0);
            Cb = __builtin_amdgcn_mfma_f32_16x16x32_f16(A[rt][1][0], bl1, Cb, 0, 0, 0);
            #pragma unroll
            for (int r = 0; r < 4; ++r) {
                float dot = Ca[r] + Cb[r];
                float d = __fadd_rn(__fsub_rn(xq[rt][r], __fmul_rn(2.0f, dot)), env);
                if (d < best[rt][r]) { best[rt][r] = d; bidx[rt][r] = kg; }
            }
        }
    }

    // ---- argmin across the 16 col-lanes of each quad (ties -> lower index)
    #pragma unroll
    for (int off = 1; off < 16; off <<= 1) {
        #pragma unroll
        for (int rt = 0; rt < 2; ++rt)
            #pragma unroll
            for (int r = 0; r < 4; ++r) {
                float ob = __shfl_xor(best[rt][r], off, 64);
                int   oi = __shfl_xor(bidx[rt][r], off, 64);
                if (ob < best[rt][r] || (ob == best[rt][r] && oi < bidx[rt][r])) {
                    best[rt][r] = ob; bidx[rt][r] = oi;
                }
            }
    }
    if (ln == 0) {
        #pragma unroll
        for (int rt = 0; rt < 2; ++rt)
            #pragma unroll
            for (int r = 0; r < 4; ++r) {
                s_best[ks][rt * 16 + q * 4 + r] = best[rt][r];
                s_bidx[ks][rt * 16 + q * 4 + r] = bidx[rt][r];
            }
    }
    __syncthreads();

    // ---- merge the 4 K-splits (lexicographic == first-occurrence argmin)
    if (tid < 32) {
        float b = 3.402823466e+38f;
        int   i = 0x7fffffff;
        #pragma unroll
        for (int s = 0; s < 4; ++s) {
            float pb = s_best[s][tid];
            int   pi = s_bidx[s][tid];
            if (pb < b || (pb == b && pi < i)) { b = pb; i = pi; }
        }
        s_fin[tid] = i;
        out[3 * (size_t)OUT_STRIDE + mbase + tid] = (float)i;  // indices as fp32
    }
    __syncthreads();

    // ---- fused epilogue: wave already holds the x-tile in A fragments.
    // x~ = hi + lo (|err| ~1e-7 relative). wave0 -> x, wave1 -> q, wave2 -> z.
    if (ks == 0) {
        #pragma unroll
        for (int rt = 0; rt < 2; ++rt) {
            float* dst = out + (size_t)(mbase + rt * 16 + ln) * E_DIM + q * 8;
            #pragma unroll
            for (int kt = 0; kt < 2; ++kt) {
                float4 u, v;
                u.x = (float)A[rt][kt][0][0] + (float)A[rt][kt][1][0];
                u.y = (float)A[rt][kt][0][1] + (float)A[rt][kt][1][1];
                u.z = (float)A[rt][kt][0][2] + (float)A[rt][kt][1][2];
                u.w = (float)A[rt][kt][0][3] + (float)A[rt][kt][1][3];
                v.x = (float)A[rt][kt][0][4] + (float)A[rt][kt][1][4];
                v.y = (float)A[rt][kt][0][5] + (float)A[rt][kt][1][5];
                v.z = (float)A[rt][kt][0][6] + (float)A[rt][kt][1][6];
                v.w = (float)A[rt][kt][0][7] + (float)A[rt][kt][1][7];
                *(float4*)(dst + kt * 32)     = u;
                *(float4*)(dst + kt * 32 + 4) = v;
            }
        }
    } else if (ks == 1) {
        #pragma unroll
        for (int rt = 0; rt < 2; ++rt) {
            const int idx = s_fin[rt * 16 + ln];
            const float* ep = emb + (size_t)idx * E_DIM + q * 8;
            float* dst = out + (size_t)OUT_STRIDE + (size_t)(mbase + rt * 16 + ln) * E_DIM + q * 8;
            #pragma unroll
            for (int kt = 0; kt < 2; ++kt) {
                *(float4*)(dst + kt * 32)     = *(const float4*)(ep + kt * 32);
                *(float4*)(dst + kt * 32 + 4) = *(const float4*)(ep + kt * 32 + 4);
            }
        }
    } else if (ks == 2) {
        #pragma unroll
        for (int rt = 0; rt < 2; ++rt) {
            const int idx = s_fin[rt * 16 + ln];
            const float* ep = emb + (size_t)idx * E_DIM + q * 8;
            float* dst = out + 2 * (size_t)OUT_STRIDE + (size_t)(mbase + rt * 16 + ln) * E_DIM + q * 8;
            #pragma unroll
            for (int kt = 0; kt < 2; ++kt) {
                float4 qv0 = *(const float4*)(ep + kt * 32);
                float4 qv1 = *(const float4*)(ep + kt * 32 + 4);
                float xt[8], z[8];
                #pragma unroll
                for (int j = 0; j < 8; ++j)
                    xt[j] = (float)A[rt][kt][0][j] + (float)A[rt][kt][1][j];
                float qq[8] = {qv0.x, qv0.y, qv0.z, qv0.w, qv1.x, qv1.y, qv1.z, qv1.w};
                #pragma unroll
                for (int j = 0; j < 8; ++j)
                    z[j] = __fsub_rn(__fadd_rn(xt[j], qq[j]), xt[j]);
                *(float4*)(dst + kt * 32)     = make_float4(z[0], z[1], z[2], z[3]);
                *(float4*)(dst + kt * 32 + 4) = make_float4(z[4], z[5], z[6], z[7]);
            }
        }
    }
}

// ---------------------------------------------------------------------------
extern "C" void kernel_launch(void* const* d_in, const int* in_sizes, int n_in,
                              void* d_out, int out_size, void* d_ws, size_t ws_size,
                              hipStream_t stream) {
    const float* x   = (const float*)d_in[0];
    const float* emb = (const float*)d_in[1];
    float* out = (float*)d_out;

    char* ws = (char*)d_ws;
    half_t* eh = (half_t*)(ws + WS_EH);
    half_t* el = (half_t*)(ws + WS_EL);
    float*  en = (float*)(ws + WS_EN);

    // codebook fp32 -> f16 hi/lo + norms (16 blocks)
    hipLaunchKernelGGL(vq_convert_kernel, dim3(K_TOTAL * 4 / 256), dim3(256), 0, stream,
                       emb, eh, el, en);
    // fused distance/argmin/epilogue: 1024 blocks x 4 waves
    hipLaunchKernelGGL(vq_fused_kernel, dim3(L_TOTAL / 32), dim3(256), 0, stream,
                       x, emb, eh, el, en, out);
}

// Round 4
// 97.082 us; speedup vs baseline: 2.2162x; 1.1102x over previous
//
#include <hip/hip_runtime.h>

#define L_TOTAL   32768
#define E_DIM     64
#define K_TOTAL   1024
#define NT_TOTAL  64                  // K_TOTAL / 16
#define OUT_STRIDE 2097152            // L_TOTAL * E_DIM

typedef _Float16 half_t;
typedef _Float16 half8  __attribute__((ext_vector_type(8)));
typedef float    floatx4 __attribute__((ext_vector_type(4)));

// Workspace layout (bytes)
#define WS_EHS 0u                      // swizzled hi frags [64 nt][2 kt][64 lane][8 h] = 128 KB
#define WS_ELS 131072u                 // swizzled lo frags                             = 128 KB
#define WS_ENS 262144u                 // broadcast norms  [64 nt][64 lane] f32         = 16 KB

// ---------------------------------------------------------------------------
// Codebook fp32 -> f16 hi/lo in MFMA-B-fragment-swizzled order + norms.
// Grid 64 (one block per 16-row tile), block 128 (kt = t>>6, lane = t&63).
// Fragment (nt,kt,lane) = e[nt*16 + (lane&15)][kt*32 + (lane>>4)*8 .. +8].
// ---------------------------------------------------------------------------
__global__ __launch_bounds__(128)
void vq_swizzle_kernel(const float* __restrict__ emb,
                       half_t* __restrict__ ehs, half_t* __restrict__ els,
                       float* __restrict__ ens) {
    __shared__ float s_p[128];
    __shared__ float s_n[16];
    const int nt   = blockIdx.x;
    const int t    = threadIdx.x;
    const int kt   = t >> 6;
    const int lane = t & 63;
    const int q    = lane >> 4;
    const int ln   = lane & 15;

    const float* src = emb + (size_t)(nt * 16 + ln) * E_DIM + kt * 32 + q * 8;
    float4 v0 = *(const float4*)src;
    float4 v1 = *(const float4*)(src + 4);
    float f[8] = {v0.x, v0.y, v0.z, v0.w, v1.x, v1.y, v1.z, v1.w};

    half8 h, l;
    float s = 0.f;
    #pragma unroll
    for (int j = 0; j < 8; ++j) {
        half_t hh = (half_t)f[j];
        half_t ll = (half_t)(f[j] - (float)hh);
        h[j] = hh;
        l[j] = ll;
        s = fmaf(f[j], f[j], s);
    }
    const size_t fo = ((size_t)(nt * 2 + kt) * 64 + lane) * 8;
    *(half8*)(ehs + fo) = h;
    *(half8*)(els + fo) = l;

    s_p[t] = s;
    __syncthreads();
    if (t < 16) {
        float n = 0.f;
        #pragma unroll
        for (int u = 0; u < 8; ++u)
            n += s_p[(u >> 2) * 64 + (u & 3) * 16 + t];
        s_n[t] = n;
    }
    __syncthreads();
    if (t < 64) ens[nt * 64 + t] = s_n[t & 15];
}

// ---------------------------------------------------------------------------
// Fused distances + argmin + epilogue.
// Block = 4 waves, all owning the SAME 64 latents (rt=0..3); wave ks scans
// K-quarter [ks*256, ks*256+256) with a per-block staggered start so the
// XCD's blocks touch the whole codebook at any instant (L2 channel spread).
// B fragments are single coalesced 1KB bursts from the swizzled codebook.
// Argmin uses lexicographic (dist, index) compare -> order-independent,
// first-occurrence semantics preserved under rotation.
// ---------------------------------------------------------------------------
__global__ __launch_bounds__(256, 2)
void vq_fused_kernel(const float* __restrict__ x,
                     const float* __restrict__ emb,
                     const half_t* __restrict__ ehs, const half_t* __restrict__ els,
                     const float* __restrict__ ens,
                     float* __restrict__ out) {
    __shared__ float s_best[4][64];
    __shared__ int   s_bidx[4][64];
    __shared__ int   s_fin[64];

    const int tid   = threadIdx.x;
    const int ks    = tid >> 6;        // K-split wave 0..3
    const int lane  = tid & 63;
    const int q     = lane >> 4;
    const int ln    = lane & 15;
    const int mbase = blockIdx.x * 64;
    const int off   = (blockIdx.x >> 3) & 15;   // stagger within K-quarter

    // ---- x tile -> hi/lo f16 A fragments (in-register), row norms
    half8 A[4][2][2];                  // [rt][kt][hi/lo]
    float nrm[4];
    #pragma unroll
    for (int rt = 0; rt < 4; ++rt) {
        const float* xr = x + (size_t)(mbase + rt * 16 + ln) * E_DIM + q * 8;
        float s = 0.f;
        #pragma unroll
        for (int kt = 0; kt < 2; ++kt) {
            float4 v0 = *(const float4*)(xr + kt * 32);
            float4 v1 = *(const float4*)(xr + kt * 32 + 4);
            float f[8] = {v0.x, v0.y, v0.z, v0.w, v1.x, v1.y, v1.z, v1.w};
            #pragma unroll
            for (int j = 0; j < 8; ++j) {
                half_t hh = (half_t)f[j];
                half_t ll = (half_t)(f[j] - (float)hh);
                A[rt][kt][0][j] = hh;
                A[rt][kt][1][j] = ll;
                s = fmaf(f[j], f[j], s);
            }
        }
        s += __shfl_xor(s, 16, 64);
        s += __shfl_xor(s, 32, 64);
        nrm[rt] = s;
    }
    floatx4 xq[4];
    #pragma unroll
    for (int rt = 0; rt < 4; ++rt)
        #pragma unroll
        for (int r = 0; r < 4; ++r)
            xq[rt][r] = __shfl(nrm[rt], q * 4 + r, 64);

    float best[4][4];
    int   bidx[4][4];
    #pragma unroll
    for (int rt = 0; rt < 4; ++rt)
        #pragma unroll
        for (int r = 0; r < 4; ++r) { best[rt][r] = 3.402823466e+38f; bidx[rt][r] = 0x7fffffff; }

    const int kq = ks * 16;            // quarter base, in nt units

    #pragma unroll 2
    for (int j = 0; j < 16; ++j) {
        const int nt = kq + ((j + off) & 15);
        const half8 bh0 = *(const half8*)(ehs + ((size_t)(nt * 2 + 0) * 64 + lane) * 8);
        const half8 bh1 = *(const half8*)(ehs + ((size_t)(nt * 2 + 1) * 64 + lane) * 8);
        const half8 bl0 = *(const half8*)(els + ((size_t)(nt * 2 + 0) * 64 + lane) * 8);
        const half8 bl1 = *(const half8*)(els + ((size_t)(nt * 2 + 1) * 64 + lane) * 8);
        const float env = ens[nt * 64 + lane];
        const int   kg  = nt * 16 + ln;

        #pragma unroll
        for (int rt = 0; rt < 4; ++rt) {
            floatx4 Ca = {0.f, 0.f, 0.f, 0.f};
            floatx4 Cb = {0.f, 0.f, 0.f, 0.f};
            Ca = __builtin_amdgcn_mfma_f32_16x16x32_f16(A[rt][0][0], bh0, Ca, 0, 0, 0);
            Ca = __builtin_amdgcn_mfma_f32_16x16x32_f16(A[rt][1][0], bh1, Ca, 0, 0, 0);
            Cb = __builtin_amdgcn_mfma_f32_16x16x32_f16(A[rt][0][1], bh0, Cb, 0, 0, 0);
            Cb = __builtin_amdgcn_mfma_f32_16x16x32_f16(A[rt][1][1], bh1, Cb, 0, 0, 0);
            Cb = __builtin_amdgcn_mfma_f32_16x16x32_f16(A[rt][0][0], bl0, Cb, 0, 0, 0);
            Cb = __builtin_amdgcn_mfma_f32_16x16x32_f16(A[rt][1][0], bl1, Cb, 0, 0, 0);
            #pragma unroll
            for (int r = 0; r < 4; ++r) {
                float dot = Ca[r] + Cb[r];
                float d = __fadd_rn(__fsub_rn(xq[rt][r], __fmul_rn(2.0f, dot)), env);
                // order-independent lexicographic argmin (first occurrence)
                if (d < best[rt][r] || (d == best[rt][r] && kg < bidx[rt][r])) {
                    best[rt][r] = d; bidx[rt][r] = kg;
                }
            }
        }
    }

    // ---- argmin across the 16 col-lanes of each quad
    #pragma unroll
    for (int o = 1; o < 16; o <<= 1) {
        #pragma unroll
        for (int rt = 0; rt < 4; ++rt)
            #pragma unroll
            for (int r = 0; r < 4; ++r) {
                float ob = __shfl_xor(best[rt][r], o, 64);
                int   oi = __shfl_xor(bidx[rt][r], o, 64);
                if (ob < best[rt][r] || (ob == best[rt][r] && oi < bidx[rt][r])) {
                    best[rt][r] = ob; bidx[rt][r] = oi;
                }
            }
    }
    if (ln == 0) {
        #pragma unroll
        for (int rt = 0; rt < 4; ++rt)
            #pragma unroll
            for (int r = 0; r < 4; ++r) {
                s_best[ks][rt * 16 + q * 4 + r] = best[rt][r];
                s_bidx[ks][rt * 16 + q * 4 + r] = bidx[rt][r];
            }
    }
    __syncthreads();

    // ---- merge the 4 K-splits (lexicographic == first-occurrence)
    if (tid < 64) {
        float b = 3.402823466e+38f;
        int   i = 0x7fffffff;
        #pragma unroll
        for (int s = 0; s < 4; ++s) {
            float pb = s_best[s][tid];
            int   pi = s_bidx[s][tid];
            if (pb < b || (pb == b && pi < i)) { b = pb; i = pi; }
        }
        s_fin[tid] = i;
        out[3 * (size_t)OUT_STRIDE + mbase + tid] = (float)i;
    }
    __syncthreads();

    // ---- fused epilogue from registers: wave0 -> x~, wave1 -> q, wave2 -> z
    if (ks == 0) {
        #pragma unroll
        for (int rt = 0; rt < 4; ++rt) {
            float* dst = out + (size_t)(mbase + rt * 16 + ln) * E_DIM + q * 8;
            #pragma unroll
            for (int kt = 0; kt < 2; ++kt) {
                float4 u, v;
                u.x = (float)A[rt][kt][0][0] + (float)A[rt][kt][1][0];
                u.y = (float)A[rt][kt][0][1] + (float)A[rt][kt][1][1];
                u.z = (float)A[rt][kt][0][2] + (float)A[rt][kt][1][2];
                u.w = (float)A[rt][kt][0][3] + (float)A[rt][kt][1][3];
                v.x = (float)A[rt][kt][0][4] + (float)A[rt][kt][1][4];
                v.y = (float)A[rt][kt][0][5] + (float)A[rt][kt][1][5];
                v.z = (float)A[rt][kt][0][6] + (float)A[rt][kt][1][6];
                v.w = (float)A[rt][kt][0][7] + (float)A[rt][kt][1][7];
                *(float4*)(dst + kt * 32)     = u;
                *(float4*)(dst + kt * 32 + 4) = v;
            }
        }
    } else if (ks == 1) {
        #pragma unroll
        for (int rt = 0; rt < 4; ++rt) {
            const int idx = s_fin[rt * 16 + ln];
            const float* ep = emb + (size_t)idx * E_DIM + q * 8;
            float* dst = out + (size_t)OUT_STRIDE + (size_t)(mbase + rt * 16 + ln) * E_DIM + q * 8;
            #pragma unroll
            for (int kt = 0; kt < 2; ++kt) {
                *(float4*)(dst + kt * 32)     = *(const float4*)(ep + kt * 32);
                *(float4*)(dst + kt * 32 + 4) = *(const float4*)(ep + kt * 32 + 4);
            }
        }
    } else if (ks == 2) {
        #pragma unroll
        for (int rt = 0; rt < 4; ++rt) {
            const int idx = s_fin[rt * 16 + ln];
            const float* ep = emb + (size_t)idx * E_DIM + q * 8;
            float* dst = out + 2 * (size_t)OUT_STRIDE + (size_t)(mbase + rt * 16 + ln) * E_DIM + q * 8;
            #pragma unroll
            for (int kt = 0; kt < 2; ++kt) {
                float4 qv0 = *(const float4*)(ep + kt * 32);
                float4 qv1 = *(const float4*)(ep + kt * 32 + 4);
                float qq[8] = {qv0.x, qv0.y, qv0.z, qv0.w, qv1.x, qv1.y, qv1.z, qv1.w};
                float z[8];
                #pragma unroll
                for (int j = 0; j < 8; ++j) {
                    float xt = (float)A[rt][kt][0][j] + (float)A[rt][kt][1][j];
                    z[j] = __fsub_rn(__fadd_rn(xt, qq[j]), xt);
                }
                *(float4*)(dst + kt * 32)     = make_float4(z[0], z[1], z[2], z[3]);
                *(float4*)(dst + kt * 32 + 4) = make_float4(z[4], z[5], z[6], z[7]);
            }
        }
    }
}

// ---------------------------------------------------------------------------
extern "C" void kernel_launch(void* const* d_in, const int* in_sizes, int n_in,
                              void* d_out, int out_size, void* d_ws, size_t ws_size,
                              hipStream_t stream) {
    const float* x   = (const float*)d_in[0];
    const float* emb = (const float*)d_in[1];
    float* out = (float*)d_out;

    char* ws = (char*)d_ws;
    half_t* ehs = (half_t*)(ws + WS_EHS);
    half_t* els = (half_t*)(ws + WS_ELS);
    float*  ens = (float*)(ws + WS_ENS);

    hipLaunchKernelGGL(vq_swizzle_kernel, dim3(NT_TOTAL), dim3(128), 0, stream,
                       emb, ehs, els, ens);
    hipLaunchKernelGGL(vq_fused_kernel, dim3(L_TOTAL / 64), dim3(256), 0, stream,
                       x, emb, ehs, els, ens, out);
}

// Round 5
// 94.631 us; speedup vs baseline: 2.2736x; 1.0259x over previous
//
#include <hip/hip_runtime.h>

#define L_TOTAL   32768
#define E_DIM     64
#define K_TOTAL   1024
#define NT_TOTAL  64                  // K_TOTAL / 16
#define OUT_STRIDE 2097152            // L_TOTAL * E_DIM
#define XPAD      68                  // LDS row pitch (floats): 68%32=4 banks/row -> 2-way max

typedef _Float16 half_t;
typedef _Float16 half8  __attribute__((ext_vector_type(8)));
typedef float    floatx4 __attribute__((ext_vector_type(4)));

// Workspace layout (bytes)
#define WS_EHS 0u                      // swizzled hi frags [64 nt][2 kt][64 lane][8 h] = 128 KB
#define WS_ELS 131072u                 // swizzled lo frags                             = 128 KB
#define WS_ENS 262144u                 // broadcast norms  [64 nt][64 lane] f32         = 16 KB

// ---------------------------------------------------------------------------
// Codebook fp32 -> f16 hi/lo in MFMA-B-fragment-swizzled order + norms.
// Fragment (nt,kt,lane) = e[nt*16 + (lane&15)][kt*32 + (lane>>4)*8 .. +8].
// ---------------------------------------------------------------------------
__global__ __launch_bounds__(128)
void vq_swizzle_kernel(const float* __restrict__ emb,
                       half_t* __restrict__ ehs, half_t* __restrict__ els,
                       float* __restrict__ ens) {
    __shared__ float s_p[128];
    __shared__ float s_n[16];
    const int nt   = blockIdx.x;
    const int t    = threadIdx.x;
    const int kt   = t >> 6;
    const int lane = t & 63;
    const int q    = lane >> 4;
    const int ln   = lane & 15;

    const float* src = emb + (size_t)(nt * 16 + ln) * E_DIM + kt * 32 + q * 8;
    float4 v0 = *(const float4*)src;
    float4 v1 = *(const float4*)(src + 4);
    float f[8] = {v0.x, v0.y, v0.z, v0.w, v1.x, v1.y, v1.z, v1.w};

    half8 h, l;
    float s = 0.f;
    #pragma unroll
    for (int j = 0; j < 8; ++j) {
        half_t hh = (half_t)f[j];
        half_t ll = (half_t)(f[j] - (float)hh);
        h[j] = hh;
        l[j] = ll;
        s = fmaf(f[j], f[j], s);
    }
    const size_t fo = ((size_t)(nt * 2 + kt) * 64 + lane) * 8;
    *(half8*)(ehs + fo) = h;
    *(half8*)(els + fo) = l;

    s_p[t] = s;
    __syncthreads();
    if (t < 16) {
        float n = 0.f;
        #pragma unroll
        for (int u = 0; u < 8; ++u)
            n += s_p[(u >> 2) * 64 + (u & 3) * 16 + t];
        s_n[t] = n;
    }
    __syncthreads();
    if (t < 64) ens[nt * 64 + t] = s_n[t & 15];
}

// ---------------------------------------------------------------------------
// Fused distances + argmin + epilogue, all-coalesced global traffic.
// Block = 4 waves over the SAME 64 latents; wave ks scans K-quarter with a
// per-block staggered start. x tile staged in LDS (coalesced float4 loads),
// fragments built from ds_read + in-register hi/lo convert. Epilogue uses a
// flat coalesced mapping; out0/out2 use the exact original fp32 x.
// ---------------------------------------------------------------------------
__global__ __launch_bounds__(256, 2)
void vq_fused_kernel(const float* __restrict__ x,
                     const float* __restrict__ emb,
                     const half_t* __restrict__ ehs, const half_t* __restrict__ els,
                     const float* __restrict__ ens,
                     float* __restrict__ out) {
    __shared__ float s_x[64 * XPAD];   // 17408 B, padded fp32 x tile
    __shared__ float s_best[4][64];
    __shared__ int   s_bidx[4][64];
    __shared__ int   s_fin[64];

    const int tid   = threadIdx.x;
    const int ks    = tid >> 6;        // K-split wave 0..3
    const int lane  = tid & 63;
    const int q     = lane >> 4;
    const int ln    = lane & 15;
    const int mbase = blockIdx.x * 64;
    const int off   = (blockIdx.x >> 3) & 15;   // stagger within K-quarter

    // ---- stage x tile: fully coalesced global float4 loads -> padded LDS
    {
        const float4* xg = (const float4*)(x + (size_t)mbase * E_DIM);
        #pragma unroll
        for (int i = 0; i < 4; ++i) {
            const int f   = i * 256 + tid;       // float4 index within tile
            const int row = f >> 4;
            const int col = (f & 15) * 4;
            *(float4*)(&s_x[row * XPAD + col]) = xg[f];
        }
    }
    __syncthreads();

    // ---- fragments from LDS (2-way bank aliasing only) + hi/lo + row norms
    half8 A[4][2][2];                  // [rt][kt][hi/lo]
    float nrm[4];
    #pragma unroll
    for (int rt = 0; rt < 4; ++rt) {
        const float* xr = &s_x[(rt * 16 + ln) * XPAD + q * 8];
        float s = 0.f;
        #pragma unroll
        for (int kt = 0; kt < 2; ++kt) {
            float4 v0 = *(const float4*)(xr + kt * 32);
            float4 v1 = *(const float4*)(xr + kt * 32 + 4);
            float f[8] = {v0.x, v0.y, v0.z, v0.w, v1.x, v1.y, v1.z, v1.w};
            #pragma unroll
            for (int j = 0; j < 8; ++j) {
                half_t hh = (half_t)f[j];
                half_t ll = (half_t)(f[j] - (float)hh);
                A[rt][kt][0][j] = hh;
                A[rt][kt][1][j] = ll;
                s = fmaf(f[j], f[j], s);
            }
        }
        s += __shfl_xor(s, 16, 64);    // sum the 4 q-slices of this row
        s += __shfl_xor(s, 32, 64);
        nrm[rt] = s;
    }
    floatx4 xq[4];
    #pragma unroll
    for (int rt = 0; rt < 4; ++rt)
        #pragma unroll
        for (int r = 0; r < 4; ++r)
            xq[rt][r] = __shfl(nrm[rt], q * 4 + r, 64);

    float best[4][4];
    int   bidx[4][4];
    #pragma unroll
    for (int rt = 0; rt < 4; ++rt)
        #pragma unroll
        for (int r = 0; r < 4; ++r) { best[rt][r] = 3.402823466e+38f; bidx[rt][r] = 0x7fffffff; }

    const int kq = ks * 16;            // quarter base, in nt units

    #pragma unroll 2
    for (int j = 0; j < 16; ++j) {
        const int nt = kq + ((j + off) & 15);
        const half8 bh0 = *(const half8*)(ehs + ((size_t)(nt * 2 + 0) * 64 + lane) * 8);
        const half8 bh1 = *(const half8*)(ehs + ((size_t)(nt * 2 + 1) * 64 + lane) * 8);
        const half8 bl0 = *(const half8*)(els + ((size_t)(nt * 2 + 0) * 64 + lane) * 8);
        const half8 bl1 = *(const half8*)(els + ((size_t)(nt * 2 + 1) * 64 + lane) * 8);
        const float env = ens[nt * 64 + lane];
        const int   kg  = nt * 16 + ln;

        #pragma unroll
        for (int rt = 0; rt < 4; ++rt) {
            floatx4 Ca = {0.f, 0.f, 0.f, 0.f};
            floatx4 Cb = {0.f, 0.f, 0.f, 0.f};
            Ca = __builtin_amdgcn_mfma_f32_16x16x32_f16(A[rt][0][0], bh0, Ca, 0, 0, 0);
            Ca = __builtin_amdgcn_mfma_f32_16x16x32_f16(A[rt][1][0], bh1, Ca, 0, 0, 0);
            Cb = __builtin_amdgcn_mfma_f32_16x16x32_f16(A[rt][0][1], bh0, Cb, 0, 0, 0);
            Cb = __builtin_amdgcn_mfma_f32_16x16x32_f16(A[rt][1][1], bh1, Cb, 0, 0, 0);
            Cb = __builtin_amdgcn_mfma_f32_16x16x32_f16(A[rt][0][0], bl0, Cb, 0, 0, 0);
            Cb = __builtin_amdgcn_mfma_f32_16x16x32_f16(A[rt][1][0], bl1, Cb, 0, 0, 0);
            #pragma unroll
            for (int r = 0; r < 4; ++r) {
                float dot = Ca[r] + Cb[r];
                float d = __fadd_rn(__fsub_rn(xq[rt][r], __fmul_rn(2.0f, dot)), env);
                // order-independent lexicographic argmin (first occurrence)
                if (d < best[rt][r] || (d == best[rt][r] && kg < bidx[rt][r])) {
                    best[rt][r] = d; bidx[rt][r] = kg;
                }
            }
        }
    }

    // ---- argmin across the 16 col-lanes of each quad
    #pragma unroll
    for (int o = 1; o < 16; o <<= 1) {
        #pragma unroll
        for (int rt = 0; rt < 4; ++rt)
            #pragma unroll
            for (int r = 0; r < 4; ++r) {
                float ob = __shfl_xor(best[rt][r], o, 64);
                int   oi = __shfl_xor(bidx[rt][r], o, 64);
                if (ob < best[rt][r] || (ob == best[rt][r] && oi < bidx[rt][r])) {
                    best[rt][r] = ob; bidx[rt][r] = oi;
                }
            }
    }
    if (ln == 0) {
        #pragma unroll
        for (int rt = 0; rt < 4; ++rt)
            #pragma unroll
            for (int r = 0; r < 4; ++r) {
                s_best[ks][rt * 16 + q * 4 + r] = best[rt][r];
                s_bidx[ks][rt * 16 + q * 4 + r] = bidx[rt][r];
            }
    }
    __syncthreads();

    // ---- merge the 4 K-splits (lexicographic == first-occurrence)
    if (tid < 64) {
        float b = 3.402823466e+38f;
        int   i = 0x7fffffff;
        #pragma unroll
        for (int s = 0; s < 4; ++s) {
            float pb = s_best[s][tid];
            int   pi = s_bidx[s][tid];
            if (pb < b || (pb == b && pi < i)) { b = pb; i = pi; }
        }
        s_fin[tid] = i;
        out[3 * (size_t)OUT_STRIDE + mbase + tid] = (float)i;  // coalesced
    }
    __syncthreads();

    // ---- coalesced epilogue: flat float4 mapping over the 64x64 tile.
    // out0 = exact x (from LDS), out1 = emb[idx], out2 = (x + q) - x.
    {
        const size_t base = (size_t)mbase * (E_DIM / 4);   // float4 units
        float4* o0 = (float4*)out + base;
        float4* o1 = (float4*)(out + OUT_STRIDE) + base;
        float4* o2 = (float4*)(out + 2 * (size_t)OUT_STRIDE) + base;
        #pragma unroll
        for (int i = 0; i < 4; ++i) {
            const int f   = i * 256 + tid;
            const int row = f >> 4;
            const int col = (f & 15) * 4;
            const float4 xv = *(const float4*)(&s_x[row * XPAD + col]);
            const int idx = s_fin[row];
            const float4 qv = *(const float4*)(emb + (size_t)idx * E_DIM + col);
            float4 z;
            z.x = __fsub_rn(__fadd_rn(xv.x, qv.x), xv.x);
            z.y = __fsub_rn(__fadd_rn(xv.y, qv.y), xv.y);
            z.z = __fsub_rn(__fadd_rn(xv.z, qv.z), xv.z);
            z.w = __fsub_rn(__fadd_rn(xv.w, qv.w), xv.w);
            o0[f] = xv;
            o1[f] = qv;
            o2[f] = z;
        }
    }
}

// ---------------------------------------------------------------------------
extern "C" void kernel_launch(void* const* d_in, const int* in_sizes, int n_in,
                              void* d_out, int out_size, void* d_ws, size_t ws_size,
                              hipStream_t stream) {
    const float* x   = (const float*)d_in[0];
    const float* emb = (const float*)d_in[1];
    float* out = (float*)d_out;

    char* ws = (char*)d_ws;
    half_t* ehs = (half_t*)(ws + WS_EHS);
    half_t* els = (half_t*)(ws + WS_ELS);
    float*  ens = (float*)(ws + WS_ENS);

    hipLaunchKernelGGL(vq_swizzle_kernel, dim3(NT_TOTAL), dim3(128), 0, stream,
                       emb, ehs, els, ens);
    hipLaunchKernelGGL(vq_fused_kernel, dim3(L_TOTAL / 64), dim3(256), 0, stream,
                       x, emb, ehs, els, ens, out);
}